// Round 2
// baseline (30213.562 us; speedup 1.0000x reference)
//
#include <hip/hip_runtime.h>
#include <stdint.h>

#define N_NEUR  1024
#define N_INP   256
#define N_OUTC  32
#define T_STEPS 500
#define BATCH   64
#define N_DEL   8
#define NB      (N_NEUR*BATCH)     // 65536 (n,b) elements, b fastest
#define HSLOTS  132                // circular history depth (max delay 128 + margin)

// ---------------------------------------------------------------------------
// W_eff[d][e][o] = dmap[d][e][o] * sign[e] * |w[e][o]|
__global__ __launch_bounds__(256) void prep_w(const float* __restrict__ w,
                                              const float* __restrict__ signs,
                                              const float* __restrict__ dmap,
                                              float* __restrict__ W) {
    size_t i = (size_t)blockIdx.x * 256 + threadIdx.x;   // < 8*1024*1024
    int r = (int)(i & (size_t)(N_NEUR * N_NEUR - 1));    // (e,o) flat
    int e = r >> 10;
    W[i] = dmap[i] * signs[e] * fabsf(w[r]);
}

// ---------------------------------------------------------------------------
// inpT[t][c][b] = inputs[b][t][c]   (LDS-tiled transpose, both sides coalesced)
__global__ __launch_bounds__(256) void transpose_inp(const float* __restrict__ inp,
                                                     float* __restrict__ inpT) {
    __shared__ float L[N_INP * 64];          // [c][b], XOR-swizzled
    int t = blockIdx.x;
    int tid = threadIdx.x;                   // = c on the read side
    for (int b = 0; b < 64; ++b) {
        float v = inp[((size_t)b * T_STEPS + t) * N_INP + tid];  // coalesced over c
        L[tid * 64 + (b ^ (tid & 63))] = v;
    }
    __syncthreads();
    int lane = tid & 63;
    int wv   = tid >> 6;
    for (int cc = 0; cc < 64; ++cc) {
        int c = cc * 4 + wv;
        inpT[((size_t)t * N_INP + c) * 64 + lane] = L[c * 64 + (lane ^ (c & 63))];
    }
}

// ---------------------------------------------------------------------------
// Pointwise update of step t for one block's slice: n in [bx*4, bx*4+4), all b.
// Computes h1 on the fly from inpT/w_in, reduces 32 split-K partials,
// updates mem/w_p, writes hist circular slot and packed spike bits.
__device__ __forceinline__ void pointwise_block(int t, int bx, int lane,
        const float* __restrict__ part, const float* __restrict__ inpT,
        const float* __restrict__ w_in, const float* __restrict__ p,
        float* __restrict__ mem, float* __restrict__ wp_arr,
        float* __restrict__ histc, unsigned long long* __restrict__ spk) {
    int n0 = bx * 4;
    // h1[t][n0+r][b] = sum_c inpT[t][c][b] * w_in[c][n0+r]
    float h1v[4] = {0.f, 0.f, 0.f, 0.f};
    const float* irow = inpT + (size_t)t * (N_INP * 64) + lane;
    const float* wcol = w_in + n0;
#pragma unroll 4
    for (int c = 0; c < N_INP; ++c) {
        float a = irow[(size_t)c * 64];                  // coalesced vload
#pragma unroll
        for (int r = 0; r < 4; ++r)                      // uniform -> s_load x4
            h1v[r] = fmaf(a, wcol[(size_t)c * N_NEUR + r], h1v[r]);
    }
    int slot = t % HSLOTS;
#pragma unroll
    for (int r = 0; r < 4; ++r) {
        int n = n0 + r;
        int i = n * 64 + lane;
        float syn = 0.f;
#pragma unroll
        for (int kc = 0; kc < 32; ++kc) syn += part[(size_t)kc * NB + i];
        float m  = mem[i];
        float w  = wp_arr[i];
        float out = (m - 1.0f > 0.0f) ? 1.0f : 0.0f;
        float pn = p[n];
        float pd = (pn < 0.0f) ? 1.0f : 0.0f;
        w = w * 0.95f + out * pn * (1.0f + pd * w);
        wp_arr[i] = w;
        histc[(size_t)slot * NB + i] = out * (1.0f + w);
        mem[i] = 0.9f * m + h1v[r] + syn - out;
        unsigned long long mask = __ballot(out > 0.0f);
        if (lane == 0) spk[(size_t)t * N_NEUR + n] = mask;
    }
}

// ---------------------------------------------------------------------------
// One simulation step (single launch):
//  - blocks 0..255 first apply the pointwise update of step t-1 (writes
//    hist slot (t-1)%HSLOTS, mem, w_p, spk bits -- nothing step-t's GEMM reads)
//  - all 2048 blocks compute split-K partials of
//      syn_p[b][o] = sum_d sum_e hist[slot(t-1-delay_d)][e][b] * W[d][e][o]
__global__ __launch_bounds__(64) void fused_step(int t,
        const float* __restrict__ W, const int* __restrict__ delays,
        const float* __restrict__ inpT, const float* __restrict__ w_in,
        const float* __restrict__ p,
        float* __restrict__ histc, float* __restrict__ mem,
        float* __restrict__ wp_arr, unsigned long long* __restrict__ spk,
        float* __restrict__ part_w, const float* __restrict__ part_r) {
    int bx = blockIdx.x;
    int lane = threadIdx.x;
    if (t > 0 && bx < 256)
        pointwise_block(t - 1, bx, lane, part_r, inpT, w_in, p, mem, wp_arr,
                        histc, spk);
    int ot = bx & 63;                 // o-tile of 16
    int kc = bx >> 6;                 // [0,32) k-chunk
    int d  = kc & 7;
    int e0 = (kc >> 3) << 8;          // e-chunk of 256
    int dl = delays[d];
    int tau = t - 1 - dl;
    int slot = ((tau % HSLOTS) + HSLOTS) % HSLOTS;   // negative tau -> zero slot
    const float* hrow  = histc + (size_t)slot * NB + (size_t)e0 * 64 + lane;
    const float* wbase = W + ((size_t)d * N_NEUR + e0) * N_NEUR + ot * 16;
    float acc[16];
#pragma unroll
    for (int j = 0; j < 16; ++j) acc[j] = 0.f;
#pragma unroll 4
    for (int e = 0; e < 256; ++e) {
        float a = hrow[(size_t)e * 64];                 // coalesced vload
        const float* wr = wbase + (size_t)e * N_NEUR;   // uniform -> s_load
#pragma unroll
        for (int j = 0; j < 16; ++j) acc[j] = fmaf(a, wr[j], acc[j]);
    }
    float* pw = part_w + (size_t)kc * NB + (size_t)(ot * 16) * 64 + lane;
#pragma unroll
    for (int j = 0; j < 16; ++j) pw[(size_t)j * 64] = acc[j];
}

// ---------------------------------------------------------------------------
__global__ __launch_bounds__(64) void tail_pointwise(int t,
        const float* __restrict__ part, const float* __restrict__ inpT,
        const float* __restrict__ w_in, const float* __restrict__ p,
        float* __restrict__ mem, float* __restrict__ wp_arr,
        float* __restrict__ histc, unsigned long long* __restrict__ spk) {
    pointwise_block(t, blockIdx.x, threadIdx.x, part, inpT, w_in, p,
                    mem, wp_arr, histc, spk);
}

// ---------------------------------------------------------------------------
// h2[t][b][o] = sum_n spk_bit(t,n,b) * w_out[n][o]
__global__ __launch_bounds__(256) void h2_gemm(const unsigned long long* __restrict__ spk,
                                               const float* __restrict__ w_out,
                                               float* __restrict__ h2) {
    int t = blockIdx.x;
    int lane = threadIdx.x & 63;     // = b
    int wv   = threadIdx.x >> 6;
    int o0 = wv * 8;
    float acc[8];
#pragma unroll
    for (int j = 0; j < 8; ++j) acc[j] = 0.f;
    for (int n = 0; n < N_NEUR; ++n) {
        unsigned long long mask = spk[(size_t)t * N_NEUR + n];   // uniform -> s_load
        float s = (float)((mask >> lane) & 1ULL);
        const float* wr = w_out + n * N_OUTC + o0;               // uniform -> s_load
#pragma unroll
        for (int j = 0; j < 8; ++j) acc[j] = fmaf(s, wr[j], acc[j]);
    }
#pragma unroll
    for (int j = 0; j < 8; ++j)
        h2[((size_t)t * BATCH + lane) * N_OUTC + o0 + j] = acc[j];
}

// ---------------------------------------------------------------------------
// out[b][t][o] : leaky-integrator scan over h2
__global__ __launch_bounds__(256) void out_scan(const float* __restrict__ h2,
                                                float* __restrict__ out) {
    int tid = blockIdx.x * 256 + threadIdx.x;   // 2048 = 64b * 32o
    int o = tid & 31;
    int b = tid >> 5;
    float acc = 0.f;
    for (int t = 0; t < T_STEPS; ++t) {
        acc = 0.9f * acc + h2[((size_t)t * BATCH + b) * N_OUTC + o];
        out[((size_t)b * T_STEPS + t) * N_OUTC + o] = acc;
    }
}

// ---------------------------------------------------------------------------
extern "C" void kernel_launch(void* const* d_in, const int* in_sizes, int n_in,
                              void* d_out, int out_size, void* d_ws, size_t ws_size,
                              hipStream_t stream) {
    (void)in_sizes; (void)n_in; (void)out_size; (void)ws_size;
    const float* inputs = (const float*)d_in[0];
    const float* w      = (const float*)d_in[1];
    const float* w_in   = (const float*)d_in[2];
    const float* w_out  = (const float*)d_in[3];
    const float* signs  = (const float*)d_in[4];
    const float* p      = (const float*)d_in[5];
    const float* dmap   = (const float*)d_in[6];
    const int*   delays = (const int*)d_in[7];
    float* out = (float*)d_out;

    // workspace layout (total 126,418,944 bytes ~= 120.6 MiB)
    float* ws    = (float*)d_ws;
    float* W     = ws;                                        //  8,388,608 f
    float* inpT  = W + (size_t)N_DEL * N_NEUR * N_NEUR;       //  8,192,000 f
    float* histc = inpT + (size_t)T_STEPS * N_INP * BATCH;    //  8,650,752 f
    float* part0 = histc + (size_t)HSLOTS * NB;               //  2,097,152 f
    float* part1 = part0 + (size_t)32 * NB;                   //  2,097,152 f
    float* mem   = part1 + (size_t)32 * NB;                   //     65,536 f
    float* wp    = mem + NB;                                  //     65,536 f
    float* h2    = wp + NB;                                   //  1,024,000 f
    unsigned long long* spk = (unsigned long long*)(h2 + (size_t)T_STEPS * BATCH * N_OUTC);

    // zero-init: circular history (wrapped reads must see 0), mem+wp (adjacent)
    hipMemsetAsync(histc, 0, (size_t)HSLOTS * NB * sizeof(float), stream);
    hipMemsetAsync(mem, 0, (size_t)2 * NB * sizeof(float), stream);

    prep_w<<<(N_DEL * N_NEUR * N_NEUR) / 256, 256, 0, stream>>>(w, signs, dmap, W);
    transpose_inp<<<T_STEPS, 256, 0, stream>>>(inputs, inpT);

    for (int t = 0; t < T_STEPS; ++t) {
        float* pw       = (t & 1) ? part1 : part0;
        const float* pr = (t & 1) ? part0 : part1;   // partials of step t-1
        fused_step<<<2048, 64, 0, stream>>>(t, W, delays, inpT, w_in, p,
                                            histc, mem, wp, spk, pw, pr);
    }
    // final pointwise for t = 499 (its partials are in part[499&1] = part1)
    tail_pointwise<<<256, 64, 0, stream>>>(T_STEPS - 1, part1, inpT, w_in, p,
                                           mem, wp, histc, spk);

    h2_gemm<<<T_STEPS, 256, 0, stream>>>(spk, w_out, h2);
    out_scan<<<8, 256, 0, stream>>>(h2, out);
}